// Round 3
// baseline (3910.407 us; speedup 1.0000x reference)
//
#include <hip/hip_runtime.h>
#include <hip/hip_bf16.h>

constexpr int U_N = 100000;
constexpr int I_N = 50000;
constexpr int KDIM = 64;
constexpr float EPSF = 1e-12f;

// cur = acc = concat(Gu, Gi)  (all f32)
__global__ void ego_init(const float* __restrict__ Gu, const float* __restrict__ Gi,
                         float* __restrict__ cur, float* __restrict__ acc, int n) {
    int i = blockIdx.x * blockDim.x + threadIdx.x;
    if (i < n) {
        const int nu = U_N * KDIM;
        float v = (i < nu) ? Gu[i] : Gi[i - nu];
        cur[i] = v;
        acc[i] = v;
    }
}

__global__ void copy_f32(const float* __restrict__ in, float* __restrict__ out, int n) {
    int i = blockIdx.x * blockDim.x + threadIdx.x;
    if (i < n) out[i] = in[i];
}

// Push-based SPMM: one wave per edge, lane k handles feature k.
// y[dst[e], k] += w[e] * x[src[e], k]
__global__ void spmm_push(const int* __restrict__ src, const int* __restrict__ dst,
                          const float* __restrict__ w, const float* __restrict__ x,
                          float* __restrict__ y, int E) {
    const int lane = threadIdx.x & 63;
    const int wave = (blockIdx.x * blockDim.x + threadIdx.x) >> 6;
    const int nw = (gridDim.x * blockDim.x) >> 6;
    const int per = (E + nw - 1) / nw;
    const int e0 = wave * per;
    const int e1 = min(E, e0 + per);
    for (int e = e0; e < e1; ++e) {
        int s = src[e];
        int d = dst[e];
        float wt = w[e];
        float v = wt * x[(size_t)s * KDIM + lane];
        unsafeAtomicAdd(&y[(size_t)d * KDIM + lane], v);
    }
}

__device__ inline float wave_sum64(float v) {
#pragma unroll
    for (int o = 32; o > 0; o >>= 1) v += __shfl_xor(v, o, 64);
    return v;
}

// Row-wise l2 normalize nxt -> cur; acc += normalized. One wave per row.
__global__ void l2norm_acc(const float* __restrict__ nxt, float* __restrict__ cur,
                           float* __restrict__ acc, int nrows) {
    const int lane = threadIdx.x & 63;
    const int r = (blockIdx.x * blockDim.x + threadIdx.x) >> 6;
    if (r < nrows) {
        size_t idx = (size_t)r * KDIM + lane;
        float v = nxt[idx];
        float ss = wave_sum64(v * v);
        float nv = v / fmaxf(sqrtf(ss), EPSF);
        cur[idx] = nv;
        acc[idx] += nv;
    }
}

// out = acc/4 (+ l2norm(gis) for item rows), stored f32. One wave per row.
__global__ void finalize(const float* __restrict__ acc, const float* __restrict__ gis,
                         float* __restrict__ out, int nrows) {
    const int lane = threadIdx.x & 63;
    const int r = (blockIdx.x * blockDim.x + threadIdx.x) >> 6;
    if (r < nrows) {
        size_t idx = (size_t)r * KDIM + lane;
        float v = acc[idx] * 0.25f;
        if (r >= U_N) {
            size_t gidx = (size_t)(r - U_N) * KDIM + lane;
            float g = gis[gidx];
            float ss = wave_sum64(g * g);
            v += g / fmaxf(sqrtf(ss), EPSF);
        }
        out[idx] = v;
    }
}

extern "C" void kernel_launch(void* const* d_in, const int* in_sizes, int n_in,
                              void* d_out, int out_size, void* d_ws, size_t ws_size,
                              hipStream_t stream) {
    const float* Gu     = (const float*)d_in[0];
    const float* Gi     = (const float*)d_in[1];
    const float* Gis    = (const float*)d_in[2];
    const float* ii_w   = (const float*)d_in[3];
    const float* ui_w   = (const float*)d_in[4];
    const int*   ii_src = (const int*)d_in[5];
    const int*   ii_dst = (const int*)d_in[6];
    const int*   ui_src = (const int*)d_in[7];
    const int*   ui_dst = (const int*)d_in[8];
    const int E_II = in_sizes[5];
    const int E_UI = in_sizes[7];

    const size_t NI = (size_t)I_N * KDIM;             // 3.2M f32
    const size_t NA = (size_t)(U_N + I_N) * KDIM;     // 9.6M f32

    float* acc = (float*)d_ws;   // NA
    float* cur = acc + NA;       // NA
    float* nxt = cur + NA;       // NA   (peak ws = 3*NA = 115.2 MB)

    float* out = (float*)d_out;

    // ---- ego init: cur = acc = [Gu; Gi] ----
    ego_init<<<(int)((NA + 255) / 256), 256, 0, stream>>>(Gu, Gi, cur, acc, (int)NA);

    // ---- 3 UI layers ----
    for (int layer = 0; layer < 3; ++layer) {
        hipMemsetAsync(nxt, 0, NA * sizeof(float), stream);
        spmm_push<<<2048, 256, 0, stream>>>(ui_src, ui_dst, ui_w, cur, nxt, E_UI);
        l2norm_acc<<<(U_N + I_N) / 4, 256, 0, stream>>>(nxt, cur, acc, U_N + I_N);
    }

    // ---- gis chain (reuses cur/nxt, dead after layer 3) ----
    // cur = f32 copy of Gis; nxt = spmm(cur); cur = spmm(nxt)
    copy_f32<<<(int)((NI + 255) / 256), 256, 0, stream>>>(Gis, cur, (int)NI);
    hipMemsetAsync(nxt, 0, NI * sizeof(float), stream);
    spmm_push<<<2048, 256, 0, stream>>>(ii_src, ii_dst, ii_w, cur, nxt, E_II);
    hipMemsetAsync(cur, 0, NI * sizeof(float), stream);
    spmm_push<<<2048, 256, 0, stream>>>(ii_src, ii_dst, ii_w, nxt, cur, E_II);

    // ---- finalize: out = acc/4 (+ l2norm(gis) on item rows) ----
    finalize<<<(U_N + I_N) / 4, 256, 0, stream>>>(acc, cur, out, U_N + I_N);
}

// Round 4
// 2374.475 us; speedup vs baseline: 1.6469x; 1.6469x over previous
//
#include <hip/hip_runtime.h>
#include <hip/hip_bf16.h>

constexpr int U_N = 100000;
constexpr int I_N = 50000;
constexpr int KDIM = 64;
constexpr float EPSF = 1e-12f;

// ---------------- CSR build ----------------

__global__ void hist_k(const int* __restrict__ dst, int* __restrict__ deg, int E) {
    int e = blockIdx.x * blockDim.x + threadIdx.x;
    if (e < E) atomicAdd(&deg[dst[e]], 1);
}

// 2-level exclusive scan, chunk = 1024 elems/block (256 thr x 4)
__global__ void scan_partial(const int* __restrict__ deg, int* __restrict__ sums, int n) {
    __shared__ int red[256];
    int b = blockIdx.x, t = threadIdx.x;
    int base = b * 1024;
    int s = 0;
    for (int j = t; j < 1024; j += 256) {
        int i = base + j;
        s += (i < n) ? deg[i] : 0;
    }
    red[t] = s;
    __syncthreads();
    for (int o = 128; o > 0; o >>= 1) {
        if (t < o) red[t] += red[t + o];
        __syncthreads();
    }
    if (t == 0) sums[b] = red[0];
}

// single block; nb <= 256. In-place exclusive scan of sums.
__global__ void scan_sums_k(int* __restrict__ sums, int nb) {
    __shared__ int a[256], b2[256];
    int t = threadIdx.x;
    int v = (t < nb) ? sums[t] : 0;
    a[t] = v;
    __syncthreads();
    int* cur = a; int* alt = b2;
    for (int o = 1; o < 256; o <<= 1) {
        int x = cur[t] + ((t >= o) ? cur[t - o] : 0);
        alt[t] = x;
        __syncthreads();
        int* tp = cur; cur = alt; alt = tp;
    }
    if (t < nb) sums[t] = cur[t] - v;   // exclusive
}

__global__ void scan_final(const int* __restrict__ deg, const int* __restrict__ sums,
                           int* __restrict__ start, int n) {
    __shared__ int a[256], b2[256];
    int b = blockIdx.x, t = threadIdx.x;
    int base = b * 1024 + t * 4;
    int d[4];
#pragma unroll
    for (int j = 0; j < 4; ++j) d[j] = (base + j < n) ? deg[base + j] : 0;
    int tsum = d[0] + d[1] + d[2] + d[3];
    a[t] = tsum;
    __syncthreads();
    int* cur = a; int* alt = b2;
    for (int o = 1; o < 256; o <<= 1) {
        int x = cur[t] + ((t >= o) ? cur[t - o] : 0);
        alt[t] = x;
        __syncthreads();
        int* tp = cur; cur = alt; alt = tp;
    }
    int run = cur[t] - tsum + sums[b];   // exclusive offset for this thread's chunk
#pragma unroll
    for (int j = 0; j < 4; ++j) {
        if (base + j <= n) start[base + j] = run;   // also writes start[n] = total
        run += d[j];
    }
}

__global__ void fill_k(const int* __restrict__ src, const int* __restrict__ dst,
                       const float* __restrict__ w, int* __restrict__ pos,
                       int* __restrict__ es, float* __restrict__ ew, int E) {
    int e = blockIdx.x * blockDim.x + threadIdx.x;
    if (e < E) {
        int p = atomicAdd(&pos[dst[e]], 1);
        es[p] = src[e];
        ew[p] = w[e];
    }
}

// ---------------- compute ----------------

__device__ inline float wave_sum64(float v) {
#pragma unroll
    for (int o = 32; o > 0; o >>= 1) v += __shfl_xor(v, o, 64);
    return v;
}

// cur = acc = concat(Gu, Gi)
__global__ void ego_init(const float* __restrict__ Gu, const float* __restrict__ Gi,
                         float* __restrict__ cur, float* __restrict__ acc, int n) {
    int i = blockIdx.x * blockDim.x + threadIdx.x;
    if (i < n) {
        const int nu = U_N * KDIM;
        float v = (i < nu) ? Gu[i] : Gi[i - nu];
        cur[i] = v;
        acc[i] = v;
    }
}

// Plain pull SPMM: y[r] = sum_j ew[j] * x[es[j]]  (one wave per row)
__global__ void spmm_pull(const int* __restrict__ start, const int* __restrict__ es,
                          const float* __restrict__ ew, const float* __restrict__ x,
                          float* __restrict__ y, int nrows) {
    const int lane = threadIdx.x & 63;
    const int r = (blockIdx.x * blockDim.x + threadIdx.x) >> 6;
    if (r >= nrows) return;
    int j0 = start[r], j1 = start[r + 1];
    float a = 0.f;
    for (int j = j0; j < j1; ++j) {
        a += ew[j] * x[(size_t)es[j] * KDIM + lane];
    }
    y[(size_t)r * KDIM + lane] = a;
}

// Pull SPMM + row l2norm; writes normalized row to cur, adds to acc.
__global__ void spmm_pull_norm(const int* __restrict__ start, const int* __restrict__ es,
                               const float* __restrict__ ew, const float* __restrict__ x,
                               float* __restrict__ cur, float* __restrict__ acc, int nrows) {
    const int lane = threadIdx.x & 63;
    const int r = (blockIdx.x * blockDim.x + threadIdx.x) >> 6;
    if (r >= nrows) return;
    int j0 = start[r], j1 = start[r + 1];
    float a = 0.f;
    for (int j = j0; j < j1; ++j) {
        a += ew[j] * x[(size_t)es[j] * KDIM + lane];
    }
    float ss = wave_sum64(a * a);
    float nv = a / fmaxf(sqrtf(ss), EPSF);
    size_t idx = (size_t)r * KDIM + lane;
    cur[idx] = nv;
    acc[idx] += nv;
}

// Last UI layer fused with finalize:
// out = (acc + l2norm(spmm_row)) / 4  (+ l2norm(gis) for item rows)
__global__ void spmm_pull_norm_final(const int* __restrict__ start, const int* __restrict__ es,
                                     const float* __restrict__ ew, const float* __restrict__ x,
                                     const float* __restrict__ gis, float* __restrict__ acc_out,
                                     int nrows) {
    const int lane = threadIdx.x & 63;
    const int r = (blockIdx.x * blockDim.x + threadIdx.x) >> 6;
    if (r >= nrows) return;
    int j0 = start[r], j1 = start[r + 1];
    float a = 0.f;
    for (int j = j0; j < j1; ++j) {
        a += ew[j] * x[(size_t)es[j] * KDIM + lane];
    }
    float ss = wave_sum64(a * a);
    float nv = a / fmaxf(sqrtf(ss), EPSF);
    size_t idx = (size_t)r * KDIM + lane;
    float v = (acc_out[idx] + nv) * 0.25f;
    if (r >= U_N) {
        size_t gidx = (size_t)(r - U_N) * KDIM + lane;
        float g = gis[gidx];
        float ss2 = wave_sum64(g * g);
        v += g / fmaxf(sqrtf(ss2), EPSF);
    }
    acc_out[idx] = v;
}

extern "C" void kernel_launch(void* const* d_in, const int* in_sizes, int n_in,
                              void* d_out, int out_size, void* d_ws, size_t ws_size,
                              hipStream_t stream) {
    const float* Gu     = (const float*)d_in[0];
    const float* Gi     = (const float*)d_in[1];
    const float* Gis    = (const float*)d_in[2];
    const float* ii_w   = (const float*)d_in[3];
    const float* ui_w   = (const float*)d_in[4];
    const int*   ii_src = (const int*)d_in[5];
    const int*   ii_dst = (const int*)d_in[6];
    const int*   ui_src = (const int*)d_in[7];
    const int*   ui_dst = (const int*)d_in[8];
    const int E_II = in_sizes[5];
    const int E_UI = in_sizes[7];

    const int NR   = U_N + I_N;                      // 150000 rows
    const size_t NI = (size_t)I_N * KDIM;            // 3.2M f32
    const size_t NA = (size_t)NR * KDIM;             // 9.6M f32

    // ---- workspace layout ----
    float* bufA = (float*)d_ws;           // NA
    float* bufB = bufA + NA;              // NA
    float* gisA = bufB + NA;              // NI
    float* gisB = gisA + NI;              // NI
    int*   ui_start = (int*)(gisB + NI);  // NR+1
    int*   ui_pos   = ui_start + (NR + 1);// NR   (doubles as deg)
    int*   ui_es    = ui_pos + NR;        // E_UI
    float* ui_ew    = (float*)(ui_es + E_UI); // E_UI
    int*   ii_start = (int*)(ui_ew + E_UI);   // I_N+1
    int*   ii_pos   = ii_start + (I_N + 1);   // I_N
    int*   ii_es    = ii_pos + I_N;           // E_II
    float* ii_ew    = (float*)(ii_es + E_II); // E_II
    int*   sums     = (int*)(ii_ew + E_II);   // <=256

    float* acc = (float*)d_out;           // accumulator lives in d_out

    const int nb_ui = (NR + 1023) / 1024;    // 147
    const int nb_ii = (I_N + 1023) / 1024;   // 49

    // ---- build UI CSR (by dst) ----
    hipMemsetAsync(ui_pos, 0, NR * sizeof(int), stream);
    hist_k<<<(E_UI + 255) / 256, 256, 0, stream>>>(ui_dst, ui_pos, E_UI);
    scan_partial<<<nb_ui, 256, 0, stream>>>(ui_pos, sums, NR);
    scan_sums_k<<<1, 256, 0, stream>>>(sums, nb_ui);
    scan_final<<<nb_ui, 256, 0, stream>>>(ui_pos, sums, ui_start, NR);
    hipMemcpyAsync(ui_pos, ui_start, NR * sizeof(int), hipMemcpyDeviceToDevice, stream);
    fill_k<<<(E_UI + 255) / 256, 256, 0, stream>>>(ui_src, ui_dst, ui_w, ui_pos, ui_es, ui_ew, E_UI);

    // ---- build II CSR (by dst) ----
    hipMemsetAsync(ii_pos, 0, I_N * sizeof(int), stream);
    hist_k<<<(E_II + 255) / 256, 256, 0, stream>>>(ii_dst, ii_pos, E_II);
    scan_partial<<<nb_ii, 256, 0, stream>>>(ii_pos, sums, I_N);
    scan_sums_k<<<1, 256, 0, stream>>>(sums, nb_ii);
    scan_final<<<nb_ii, 256, 0, stream>>>(ii_pos, sums, ii_start, I_N);
    hipMemcpyAsync(ii_pos, ii_start, I_N * sizeof(int), hipMemcpyDeviceToDevice, stream);
    fill_k<<<(E_II + 255) / 256, 256, 0, stream>>>(ii_src, ii_dst, ii_w, ii_pos, ii_es, ii_ew, E_II);

    // ---- gis chain: gisA = spmm(Gis); gisB = spmm(gisA) ----
    spmm_pull<<<(I_N + 3) / 4, 256, 0, stream>>>(ii_start, ii_es, ii_ew, Gis, gisA, I_N);
    spmm_pull<<<(I_N + 3) / 4, 256, 0, stream>>>(ii_start, ii_es, ii_ew, gisA, gisB, I_N);

    // ---- ego init: bufA = acc = [Gu; Gi] ----
    ego_init<<<(int)((NA + 255) / 256), 256, 0, stream>>>(Gu, Gi, bufA, acc, (int)NA);

    // ---- 3 UI layers (norm fused; last one fuses finalize) ----
    spmm_pull_norm<<<(NR + 3) / 4, 256, 0, stream>>>(ui_start, ui_es, ui_ew, bufA, bufB, acc, NR);
    spmm_pull_norm<<<(NR + 3) / 4, 256, 0, stream>>>(ui_start, ui_es, ui_ew, bufB, bufA, acc, NR);
    spmm_pull_norm_final<<<(NR + 3) / 4, 256, 0, stream>>>(ui_start, ui_es, ui_ew, bufA, gisB, acc, NR);
}

// Round 5
// 1390.459 us; speedup vs baseline: 2.8123x; 1.7077x over previous
//
#include <hip/hip_runtime.h>
#include <hip/hip_bf16.h>

constexpr int U_N = 100000;
constexpr int I_N = 50000;
constexpr int KDIM = 64;
constexpr float EPSF = 1e-12f;

typedef float f4 __attribute__((ext_vector_type(4)));

__device__ inline f4 ld4(const float* p) { return *(const f4*)p; }

// ---------------- CSR build ----------------

__global__ void hist_k(const int* __restrict__ dst, int* __restrict__ deg, int E) {
    int e = blockIdx.x * blockDim.x + threadIdx.x;
    if (e < E) atomicAdd(&deg[dst[e]], 1);
}

// 2-level exclusive scan, chunk = 1024 elems/block (256 thr x 4)
__global__ void scan_partial(const int* __restrict__ deg, int* __restrict__ sums, int n) {
    __shared__ int red[256];
    int b = blockIdx.x, t = threadIdx.x;
    int base = b * 1024;
    int s = 0;
    for (int j = t; j < 1024; j += 256) {
        int i = base + j;
        s += (i < n) ? deg[i] : 0;
    }
    red[t] = s;
    __syncthreads();
    for (int o = 128; o > 0; o >>= 1) {
        if (t < o) red[t] += red[t + o];
        __syncthreads();
    }
    if (t == 0) sums[b] = red[0];
}

// single block; nb <= 256. In-place exclusive scan of sums.
__global__ void scan_sums_k(int* __restrict__ sums, int nb) {
    __shared__ int a[256], b2[256];
    int t = threadIdx.x;
    int v = (t < nb) ? sums[t] : 0;
    a[t] = v;
    __syncthreads();
    int* cur = a; int* alt = b2;
    for (int o = 1; o < 256; o <<= 1) {
        int x = cur[t] + ((t >= o) ? cur[t - o] : 0);
        alt[t] = x;
        __syncthreads();
        int* tp = cur; cur = alt; alt = tp;
    }
    if (t < nb) sums[t] = cur[t] - v;   // exclusive
}

// writes start[0..n] (incl. total) and pos[0..n-1] (= start copy for fill)
__global__ void scan_final(const int* __restrict__ deg, const int* __restrict__ sums,
                           int* __restrict__ start, int* __restrict__ pos, int n) {
    __shared__ int a[256], b2[256];
    int b = blockIdx.x, t = threadIdx.x;
    int base = b * 1024 + t * 4;
    int d[4];
#pragma unroll
    for (int j = 0; j < 4; ++j) d[j] = (base + j < n) ? deg[base + j] : 0;
    int tsum = d[0] + d[1] + d[2] + d[3];
    a[t] = tsum;
    __syncthreads();
    int* cur = a; int* alt = b2;
    for (int o = 1; o < 256; o <<= 1) {
        int x = cur[t] + ((t >= o) ? cur[t - o] : 0);
        alt[t] = x;
        __syncthreads();
        int* tp = cur; cur = alt; alt = tp;
    }
    int run = cur[t] - tsum + sums[b];   // exclusive offset for this thread's chunk
#pragma unroll
    for (int j = 0; j < 4; ++j) {
        if (base + j <= n) start[base + j] = run;   // also writes start[n] = total
        if (base + j < n)  pos[base + j] = run;
        run += d[j];
    }
}

__global__ void fill_k(const int* __restrict__ src, const int* __restrict__ dst,
                       const float* __restrict__ w, int* __restrict__ pos,
                       int2* __restrict__ e2, int E) {
    int e = blockIdx.x * blockDim.x + threadIdx.x;
    if (e < E) {
        int p = atomicAdd(&pos[dst[e]], 1);
        e2[p] = make_int2(src[e], __float_as_int(w[e]));
    }
}

// ---------------- compute ----------------

// sum within 16-lane group (all offsets stay inside the group)
__device__ inline float group16_sum(float v) {
    v += __shfl_xor(v, 1, 64);
    v += __shfl_xor(v, 2, 64);
    v += __shfl_xor(v, 4, 64);
    v += __shfl_xor(v, 8, 64);
    return v;
}

// Gather-accumulate one CSR row. Wave layout: g = lane>>4 (edge slot),
// l = lane&15 (float4 feature slot). 4 edges per iteration, unrolled x2
// => 8 edges / 2KB in flight per loop body. Returns full row sum (all lanes).
__device__ inline f4 spmm_row(const int2* __restrict__ e2, int j0, int j1,
                              const float* __restrict__ x, int g, int l) {
    f4 a0 = {0.f, 0.f, 0.f, 0.f};
    f4 a1 = {0.f, 0.f, 0.f, 0.f};
    int j = j0;
    for (; j + 8 <= j1; j += 8) {
        int2 ea = e2[j + g];
        int2 eb = e2[j + 4 + g];
        f4 va = ld4(x + (size_t)ea.x * KDIM + l * 4);
        f4 vb = ld4(x + (size_t)eb.x * KDIM + l * 4);
        a0 += __int_as_float(ea.y) * va;
        a1 += __int_as_float(eb.y) * vb;
    }
    for (; j < j1; j += 4) {
        if (j + g < j1) {
            int2 ea = e2[j + g];
            f4 va = ld4(x + (size_t)ea.x * KDIM + l * 4);
            a0 += __int_as_float(ea.y) * va;
        }
    }
    f4 a = a0 + a1;
#pragma unroll
    for (int c = 0; c < 4; ++c) {
        a[c] += __shfl_xor(a[c], 16, 64);
        a[c] += __shfl_xor(a[c], 32, 64);
    }
    return a;
}

// cur = acc = concat(Gu, Gi), float4-vectorized over n4 = NA/4
__global__ void ego_init4(const float* __restrict__ Gu, const float* __restrict__ Gi,
                          float* __restrict__ cur, float* __restrict__ acc, int n4) {
    int i = blockIdx.x * blockDim.x + threadIdx.x;
    if (i < n4) {
        const int nu4 = U_N * (KDIM / 4);
        f4 v = (i < nu4) ? ld4(Gu + (size_t)i * 4) : ld4(Gi + (size_t)(i - nu4) * 4);
        *(f4*)(cur + (size_t)i * 4) = v;
        *(f4*)(acc + (size_t)i * 4) = v;
    }
}

// Plain pull SPMM (gis chain): y[r] = sum_j w_j * x[src_j]
__global__ void spmm_pull(const int* __restrict__ start, const int2* __restrict__ e2,
                          const float* __restrict__ x, float* __restrict__ y, int nrows) {
    const int lane = threadIdx.x & 63;
    const int g = lane >> 4, l = lane & 15;
    const int r = (blockIdx.x * blockDim.x + threadIdx.x) >> 6;
    if (r >= nrows) return;
    f4 a = spmm_row(e2, start[r], start[r + 1], x, g, l);
    if (g == 0) *(f4*)(y + (size_t)r * KDIM + l * 4) = a;
}

// Pull SPMM + row l2norm; writes normalized row to cur, adds to acc.
__global__ void spmm_pull_norm(const int* __restrict__ start, const int2* __restrict__ e2,
                               const float* __restrict__ x, float* __restrict__ cur,
                               float* __restrict__ acc, int nrows) {
    const int lane = threadIdx.x & 63;
    const int g = lane >> 4, l = lane & 15;
    const int r = (blockIdx.x * blockDim.x + threadIdx.x) >> 6;
    if (r >= nrows) return;
    f4 a = spmm_row(e2, start[r], start[r + 1], x, g, l);
    float ss = group16_sum(a[0] * a[0] + a[1] * a[1] + a[2] * a[2] + a[3] * a[3]);
    f4 nv = a * (1.f / fmaxf(sqrtf(ss), EPSF));
    if (g == 0) {
        size_t idx = (size_t)r * KDIM + l * 4;
        *(f4*)(cur + idx) = nv;
        f4 old = ld4(acc + idx);
        *(f4*)(acc + idx) = old + nv;
    }
}

// Last UI layer fused with finalize:
// out = (acc + l2norm(spmm_row)) / 4  (+ l2norm(gis) for item rows)
__global__ void spmm_pull_norm_final(const int* __restrict__ start, const int2* __restrict__ e2,
                                     const float* __restrict__ x, const float* __restrict__ gis,
                                     float* __restrict__ acc_out, int nrows) {
    const int lane = threadIdx.x & 63;
    const int g = lane >> 4, l = lane & 15;
    const int r = (blockIdx.x * blockDim.x + threadIdx.x) >> 6;
    if (r >= nrows) return;
    f4 a = spmm_row(e2, start[r], start[r + 1], x, g, l);
    float ss = group16_sum(a[0] * a[0] + a[1] * a[1] + a[2] * a[2] + a[3] * a[3]);
    f4 nv = a * (1.f / fmaxf(sqrtf(ss), EPSF));
    size_t idx = (size_t)r * KDIM + l * 4;
    f4 v = (ld4(acc_out + idx) + nv) * 0.25f;
    if (r >= U_N) {
        const float* gp = gis + (size_t)(r - U_N) * KDIM + l * 4;
        f4 gv = ld4(gp);
        float ss2 = group16_sum(gv[0] * gv[0] + gv[1] * gv[1] + gv[2] * gv[2] + gv[3] * gv[3]);
        v += gv * (1.f / fmaxf(sqrtf(ss2), EPSF));
    }
    if (g == 0) *(f4*)(acc_out + idx) = v;
}

extern "C" void kernel_launch(void* const* d_in, const int* in_sizes, int n_in,
                              void* d_out, int out_size, void* d_ws, size_t ws_size,
                              hipStream_t stream) {
    const float* Gu     = (const float*)d_in[0];
    const float* Gi     = (const float*)d_in[1];
    const float* Gis    = (const float*)d_in[2];
    const float* ii_w   = (const float*)d_in[3];
    const float* ui_w   = (const float*)d_in[4];
    const int*   ii_src = (const int*)d_in[5];
    const int*   ii_dst = (const int*)d_in[6];
    const int*   ui_src = (const int*)d_in[7];
    const int*   ui_dst = (const int*)d_in[8];
    const int E_II = in_sizes[5];
    const int E_UI = in_sizes[7];

    const int NR    = U_N + I_N;                     // 150000 rows
    const size_t NI = (size_t)I_N * KDIM;            // 3.2M f32
    const size_t NA = (size_t)NR * KDIM;             // 9.6M f32

    // ---- workspace layout (8B-aligned segments first-by-construction) ----
    float* bufA = (float*)d_ws;            // NA
    float* bufB = bufA + NA;               // NA   (also hosts gisA transiently)
    float* gisB = bufB + NA;               // NI
    int2*  ui_e = (int2*)(gisB + NI);      // E_UI (8B aligned: 22.4M floats before = even)
    int2*  ii_e = ui_e + E_UI;             // E_II
    int*   ui_start = (int*)(ii_e + E_II); // NR+1
    int*   ui_pos   = ui_start + (NR + 1); // NR
    int*   ii_start = ui_pos + NR;         // I_N+1
    int*   ii_pos   = ii_start + (I_N + 1);// I_N
    int*   sums     = ii_pos + I_N;        // <=256

    float* acc = (float*)d_out;            // accumulator lives in d_out

    const int nb_ui = (NR + 1023) / 1024;    // 147
    const int nb_ii = (I_N + 1023) / 1024;   // 49

    // ---- build UI CSR (by dst) ----
    hipMemsetAsync(ui_pos, 0, NR * sizeof(int), stream);
    hist_k<<<(E_UI + 255) / 256, 256, 0, stream>>>(ui_dst, ui_pos, E_UI);
    scan_partial<<<nb_ui, 256, 0, stream>>>(ui_pos, sums, NR);
    scan_sums_k<<<1, 256, 0, stream>>>(sums, nb_ui);
    scan_final<<<nb_ui, 256, 0, stream>>>(ui_pos, sums, ui_start, ui_pos, NR);
    fill_k<<<(E_UI + 255) / 256, 256, 0, stream>>>(ui_src, ui_dst, ui_w, ui_pos, ui_e, E_UI);

    // ---- build II CSR (by dst) ----
    hipMemsetAsync(ii_pos, 0, I_N * sizeof(int), stream);
    hist_k<<<(E_II + 255) / 256, 256, 0, stream>>>(ii_dst, ii_pos, E_II);
    scan_partial<<<nb_ii, 256, 0, stream>>>(ii_pos, sums, I_N);
    scan_sums_k<<<1, 256, 0, stream>>>(sums, nb_ii);
    scan_final<<<nb_ii, 256, 0, stream>>>(ii_pos, sums, ii_start, ii_pos, I_N);
    fill_k<<<(E_II + 255) / 256, 256, 0, stream>>>(ii_src, ii_dst, ii_w, ii_pos, ii_e, E_II);

    // ---- gis chain: bufB = spmm(Gis); gisB = spmm(bufB) ----
    spmm_pull<<<(I_N + 3) / 4, 256, 0, stream>>>(ii_start, ii_e, Gis, bufB, I_N);
    spmm_pull<<<(I_N + 3) / 4, 256, 0, stream>>>(ii_start, ii_e, bufB, gisB, I_N);

    // ---- ego init: bufA = acc = [Gu; Gi] ----
    ego_init4<<<(int)((NA / 4 + 255) / 256), 256, 0, stream>>>(Gu, Gi, bufA, acc, (int)(NA / 4));

    // ---- 3 UI layers (norm fused; last one fuses finalize) ----
    spmm_pull_norm<<<(NR + 3) / 4, 256, 0, stream>>>(ui_start, ui_e, bufA, bufB, acc, NR);
    spmm_pull_norm<<<(NR + 3) / 4, 256, 0, stream>>>(ui_start, ui_e, bufB, bufA, acc, NR);
    spmm_pull_norm_final<<<(NR + 3) / 4, 256, 0, stream>>>(ui_start, ui_e, bufA, gisB, acc, NR);
}

// Round 6
// 1153.901 us; speedup vs baseline: 3.3889x; 1.2050x over previous
//
#include <hip/hip_runtime.h>
#include <hip/hip_bf16.h>

constexpr int U_N = 100000;
constexpr int I_N = 50000;
constexpr int KDIM = 64;
constexpr float EPSF = 1e-12f;

typedef float f4 __attribute__((ext_vector_type(4)));
typedef unsigned short u16;

__device__ inline f4 ld4(const float* p) { return *(const f4*)p; }

// pack two f32 -> two bf16 (RNE) in one uint32
__device__ inline unsigned pack_bf16(float a, float b) {
    unsigned ua = __float_as_uint(a);
    unsigned ub = __float_as_uint(b);
    ua += 0x7fffu + ((ua >> 16) & 1u);
    ub += 0x7fffu + ((ub >> 16) & 1u);
    return (ua >> 16) | (ub & 0xffff0000u);
}

// unpack 8 bf16 (uint4) -> 8 f32
__device__ inline void bf8_to_f32(uint4 u, float* f) {
    unsigned w0 = u.x, w1 = u.y, w2 = u.z, w3 = u.w;
    f[0] = __uint_as_float(w0 << 16);  f[1] = __uint_as_float(w0 & 0xffff0000u);
    f[2] = __uint_as_float(w1 << 16);  f[3] = __uint_as_float(w1 & 0xffff0000u);
    f[4] = __uint_as_float(w2 << 16);  f[5] = __uint_as_float(w2 & 0xffff0000u);
    f[6] = __uint_as_float(w3 << 16);  f[7] = __uint_as_float(w3 & 0xffff0000u);
}

// ---------------- CSR build ----------------

__global__ void hist_k4(const int* __restrict__ dst, int* __restrict__ deg, int E) {
    int i = (blockIdx.x * blockDim.x + threadIdx.x) * 4;
    if (i + 4 <= E) {
        int4 d = *(const int4*)(dst + i);
        atomicAdd(&deg[d.x], 1);
        atomicAdd(&deg[d.y], 1);
        atomicAdd(&deg[d.z], 1);
        atomicAdd(&deg[d.w], 1);
    } else {
        for (int k = i; k < E; ++k) atomicAdd(&deg[dst[k]], 1);
    }
}

__global__ void scan_partial(const int* __restrict__ deg, int* __restrict__ sums, int n) {
    __shared__ int red[256];
    int b = blockIdx.x, t = threadIdx.x;
    int base = b * 1024;
    int s = 0;
    for (int j = t; j < 1024; j += 256) {
        int i = base + j;
        s += (i < n) ? deg[i] : 0;
    }
    red[t] = s;
    __syncthreads();
    for (int o = 128; o > 0; o >>= 1) {
        if (t < o) red[t] += red[t + o];
        __syncthreads();
    }
    if (t == 0) sums[b] = red[0];
}

__global__ void scan_sums_k(int* __restrict__ sums, int nb) {
    __shared__ int a[256], b2[256];
    int t = threadIdx.x;
    int v = (t < nb) ? sums[t] : 0;
    a[t] = v;
    __syncthreads();
    int* cur = a; int* alt = b2;
    for (int o = 1; o < 256; o <<= 1) {
        int x = cur[t] + ((t >= o) ? cur[t - o] : 0);
        alt[t] = x;
        __syncthreads();
        int* tp = cur; cur = alt; alt = tp;
    }
    if (t < nb) sums[t] = cur[t] - v;   // exclusive
}

__global__ void scan_final(const int* __restrict__ deg, const int* __restrict__ sums,
                           int* __restrict__ start, int* __restrict__ pos, int n) {
    __shared__ int a[256], b2[256];
    int b = blockIdx.x, t = threadIdx.x;
    int base = b * 1024 + t * 4;
    int d[4];
#pragma unroll
    for (int j = 0; j < 4; ++j) d[j] = (base + j < n) ? deg[base + j] : 0;
    int tsum = d[0] + d[1] + d[2] + d[3];
    a[t] = tsum;
    __syncthreads();
    int* cur = a; int* alt = b2;
    for (int o = 1; o < 256; o <<= 1) {
        int x = cur[t] + ((t >= o) ? cur[t - o] : 0);
        alt[t] = x;
        __syncthreads();
        int* tp = cur; cur = alt; alt = tp;
    }
    int run = cur[t] - tsum + sums[b];
#pragma unroll
    for (int j = 0; j < 4; ++j) {
        if (base + j <= n) start[base + j] = run;   // also writes start[n] = total
        if (base + j < n)  pos[base + j] = run;
        run += d[j];
    }
}

__global__ void fill_k(const int* __restrict__ src, const int* __restrict__ dst,
                       const float* __restrict__ w, int* __restrict__ pos,
                       int2* __restrict__ e2, int E) {
    int e = blockIdx.x * blockDim.x + threadIdx.x;
    if (e < E) {
        int p = atomicAdd(&pos[dst[e]], 1);
        e2[p] = make_int2(src[e], __float_as_int(w[e]));
    }
}

// ---------------- compute ----------------

__device__ inline float group8_sum(float v) {
    v += __shfl_xor(v, 1, 64);
    v += __shfl_xor(v, 2, 64);
    v += __shfl_xor(v, 4, 64);
    return v;
}

// Gather-accumulate one CSR row from bf16 table.
// Wave layout: g = lane>>3 (8 edge slots), l = lane&7 (8 features each, 16B load).
// 16 edges / 2KB in flight per unrolled body. Result: full row sums in a[0..7],
// duplicated across groups.
__device__ inline void spmm_row_bf(const int2* __restrict__ e2, int j0, int j1,
                                   const u16* __restrict__ x, int g, int l,
                                   float a[8]) {
    float a0[8] = {0, 0, 0, 0, 0, 0, 0, 0};
    float a1[8] = {0, 0, 0, 0, 0, 0, 0, 0};
    int j = j0;
    for (; j + 16 <= j1; j += 16) {
        int2 ea = e2[j + g];
        int2 eb = e2[j + 8 + g];
        uint4 ua = *(const uint4*)(x + (size_t)ea.x * KDIM + l * 8);
        uint4 ub = *(const uint4*)(x + (size_t)eb.x * KDIM + l * 8);
        float wa = __int_as_float(ea.y), wb = __int_as_float(eb.y);
        float fa[8], fb[8];
        bf8_to_f32(ua, fa);
        bf8_to_f32(ub, fb);
#pragma unroll
        for (int c = 0; c < 8; ++c) {
            a0[c] += wa * fa[c];
            a1[c] += wb * fb[c];
        }
    }
    for (; j < j1; j += 8) {
        if (j + g < j1) {
            int2 ea = e2[j + g];
            uint4 ua = *(const uint4*)(x + (size_t)ea.x * KDIM + l * 8);
            float wa = __int_as_float(ea.y);
            float fa[8];
            bf8_to_f32(ua, fa);
#pragma unroll
            for (int c = 0; c < 8; ++c) a0[c] += wa * fa[c];
        }
    }
#pragma unroll
    for (int c = 0; c < 8; ++c) {
        float v = a0[c] + a1[c];
        v += __shfl_xor(v, 8, 64);
        v += __shfl_xor(v, 16, 64);
        v += __shfl_xor(v, 32, 64);
        a[c] = v;
    }
}

// cur(bf16) = acc(f32) = concat(Gu, Gi); one thread per 8 elements
__global__ void ego_init8(const float* __restrict__ Gu, const float* __restrict__ Gi,
                          u16* __restrict__ cur, float* __restrict__ acc, int n8) {
    int i = blockIdx.x * blockDim.x + threadIdx.x;
    if (i >= n8) return;
    const int nu8 = U_N * (KDIM / 8);
    const float* p = (i < nu8) ? Gu + (size_t)i * 8 : Gi + (size_t)(i - nu8) * 8;
    f4 v0 = ld4(p);
    f4 v1 = ld4(p + 4);
    uint4 pk;
    pk.x = pack_bf16(v0.x, v0.y);
    pk.y = pack_bf16(v0.z, v0.w);
    pk.z = pack_bf16(v1.x, v1.y);
    pk.w = pack_bf16(v1.z, v1.w);
    *(uint4*)(cur + (size_t)i * 8) = pk;
    *(f4*)(acc + (size_t)i * 8) = v0;
    *(f4*)(acc + (size_t)i * 8 + 4) = v1;
}

// f32 -> bf16 bulk convert, 8 elems/thread
__global__ void cvt_bf8(const float* __restrict__ in, u16* __restrict__ out, int n8) {
    int i = blockIdx.x * blockDim.x + threadIdx.x;
    if (i >= n8) return;
    f4 v0 = ld4(in + (size_t)i * 8);
    f4 v1 = ld4(in + (size_t)i * 8 + 4);
    uint4 pk;
    pk.x = pack_bf16(v0.x, v0.y);
    pk.y = pack_bf16(v0.z, v0.w);
    pk.z = pack_bf16(v1.x, v1.y);
    pk.w = pack_bf16(v1.z, v1.w);
    *(uint4*)(out + (size_t)i * 8) = pk;
}

// pull SPMM, bf16 in -> bf16 out (gis hop 1)
__global__ void spmm_pull_bf(const int* __restrict__ start, const int2* __restrict__ e2,
                             const u16* __restrict__ x, u16* __restrict__ y, int nrows) {
    const int lane = threadIdx.x & 63;
    const int g = lane >> 3, l = lane & 7;
    const int r = (blockIdx.x * blockDim.x + threadIdx.x) >> 6;
    if (r >= nrows) return;
    float a[8];
    spmm_row_bf(e2, start[r], start[r + 1], x, g, l, a);
    if (g == 0) {
        uint4 pk;
        pk.x = pack_bf16(a[0], a[1]);
        pk.y = pack_bf16(a[2], a[3]);
        pk.z = pack_bf16(a[4], a[5]);
        pk.w = pack_bf16(a[6], a[7]);
        *(uint4*)(y + (size_t)r * KDIM + l * 8) = pk;
    }
}

// pull SPMM, bf16 in -> f32 out (gis hop 2)
__global__ void spmm_pull_f32(const int* __restrict__ start, const int2* __restrict__ e2,
                              const u16* __restrict__ x, float* __restrict__ y, int nrows) {
    const int lane = threadIdx.x & 63;
    const int g = lane >> 3, l = lane & 7;
    const int r = (blockIdx.x * blockDim.x + threadIdx.x) >> 6;
    if (r >= nrows) return;
    float a[8];
    spmm_row_bf(e2, start[r], start[r + 1], x, g, l, a);
    if (g == 0) {
        float* yp = y + (size_t)r * KDIM + l * 8;
        *(f4*)yp = f4{a[0], a[1], a[2], a[3]};
        *(f4*)(yp + 4) = f4{a[4], a[5], a[6], a[7]};
    }
}

// pull SPMM + l2norm; normalized row -> cur (bf16), acc += normalized (f32)
__global__ void spmm_pull_norm(const int* __restrict__ start, const int2* __restrict__ e2,
                               const u16* __restrict__ x, u16* __restrict__ cur,
                               float* __restrict__ acc, int nrows) {
    const int lane = threadIdx.x & 63;
    const int g = lane >> 3, l = lane & 7;
    const int r = (blockIdx.x * blockDim.x + threadIdx.x) >> 6;
    if (r >= nrows) return;
    float a[8];
    spmm_row_bf(e2, start[r], start[r + 1], x, g, l, a);
    float loc = 0.f;
#pragma unroll
    for (int c = 0; c < 8; ++c) loc += a[c] * a[c];
    float ss = group8_sum(loc);
    float inv = 1.f / fmaxf(sqrtf(ss), EPSF);
    if (g == 0) {
        uint4 pk;
        pk.x = pack_bf16(a[0] * inv, a[1] * inv);
        pk.y = pack_bf16(a[2] * inv, a[3] * inv);
        pk.z = pack_bf16(a[4] * inv, a[5] * inv);
        pk.w = pack_bf16(a[6] * inv, a[7] * inv);
        *(uint4*)(cur + (size_t)r * KDIM + l * 8) = pk;
        float* ap = acc + (size_t)r * KDIM + l * 8;
        f4 o0 = ld4(ap);
        f4 o1 = ld4(ap + 4);
        o0 += f4{a[0] * inv, a[1] * inv, a[2] * inv, a[3] * inv};
        o1 += f4{a[4] * inv, a[5] * inv, a[6] * inv, a[7] * inv};
        *(f4*)ap = o0;
        *(f4*)(ap + 4) = o1;
    }
}

// Last UI layer fused with finalize:
// out = (acc + l2norm(spmm_row)) / 4  (+ l2norm(gis) for item rows), f32 out
__global__ void spmm_pull_norm_final(const int* __restrict__ start, const int2* __restrict__ e2,
                                     const u16* __restrict__ x, const float* __restrict__ gis,
                                     float* __restrict__ acc_out, int nrows) {
    const int lane = threadIdx.x & 63;
    const int g = lane >> 3, l = lane & 7;
    const int r = (blockIdx.x * blockDim.x + threadIdx.x) >> 6;
    if (r >= nrows) return;
    float a[8];
    spmm_row_bf(e2, start[r], start[r + 1], x, g, l, a);
    float loc = 0.f;
#pragma unroll
    for (int c = 0; c < 8; ++c) loc += a[c] * a[c];
    float ss = group8_sum(loc);
    float inv = 1.f / fmaxf(sqrtf(ss), EPSF);
    if (g != 0) return;
    float* ap = acc_out + (size_t)r * KDIM + l * 8;
    f4 v0 = (ld4(ap) + f4{a[0] * inv, a[1] * inv, a[2] * inv, a[3] * inv}) * 0.25f;
    f4 v1 = (ld4(ap + 4) + f4{a[4] * inv, a[5] * inv, a[6] * inv, a[7] * inv}) * 0.25f;
    if (r >= U_N) {
        const float* gp = gis + (size_t)(r - U_N) * KDIM + l * 8;
        f4 g0 = ld4(gp);
        f4 g1 = ld4(gp + 4);
        float loc2 = g0.x * g0.x + g0.y * g0.y + g0.z * g0.z + g0.w * g0.w
                   + g1.x * g1.x + g1.y * g1.y + g1.z * g1.z + g1.w * g1.w;
        // only lanes 0..7 here; group8_sum works within this group
        float ss2 = group8_sum(loc2);
        float inv2 = 1.f / fmaxf(sqrtf(ss2), EPSF);
        v0 += g0 * inv2;
        v1 += g1 * inv2;
    }
    *(f4*)ap = v0;
    *(f4*)(ap + 4) = v1;
}

extern "C" void kernel_launch(void* const* d_in, const int* in_sizes, int n_in,
                              void* d_out, int out_size, void* d_ws, size_t ws_size,
                              hipStream_t stream) {
    const float* Gu     = (const float*)d_in[0];
    const float* Gi     = (const float*)d_in[1];
    const float* Gis    = (const float*)d_in[2];
    const float* ii_w   = (const float*)d_in[3];
    const float* ui_w   = (const float*)d_in[4];
    const int*   ii_src = (const int*)d_in[5];
    const int*   ii_dst = (const int*)d_in[6];
    const int*   ui_src = (const int*)d_in[7];
    const int*   ui_dst = (const int*)d_in[8];
    const int E_II = in_sizes[5];
    const int E_UI = in_sizes[7];

    const int NR    = U_N + I_N;                     // 150000 rows
    const size_t NI = (size_t)I_N * KDIM;            // 3.2M elems
    const size_t NA = (size_t)NR * KDIM;             // 9.6M elems

    // ---- workspace layout (all segments 16B-aligned by construction) ----
    u16*  bufA = (u16*)d_ws;               // NA bf16 (19.2MB)
    u16*  bufB = bufA + NA;                // NA bf16
    u16*  gis0 = bufB + NA;                // NI bf16 (cvt of Gis)
    u16*  gisA = gis0 + NI;                // NI bf16
    float* gisB = (float*)(gisA + NI);     // NI f32
    int2*  ui_e = (int2*)(gisB + NI);      // E_UI
    int2*  ii_e = ui_e + E_UI;             // E_II
    int*   ui_start = (int*)(ii_e + E_II); // NR+1
    int*   ui_pos   = ui_start + (NR + 1); // NR
    int*   ii_start = ui_pos + NR;         // I_N+1
    int*   ii_pos   = ii_start + (I_N + 1);// I_N
    int*   sums     = ii_pos + I_N;        // <=256

    float* acc = (float*)d_out;            // f32 accumulator lives in d_out

    const int nb_ui = (NR + 1023) / 1024;    // 147
    const int nb_ii = (I_N + 1023) / 1024;   // 49

    // ---- build UI CSR (by dst) ----
    hipMemsetAsync(ui_pos, 0, NR * sizeof(int), stream);
    hist_k4<<<(E_UI / 4 + 255) / 256, 256, 0, stream>>>(ui_dst, ui_pos, E_UI);
    scan_partial<<<nb_ui, 256, 0, stream>>>(ui_pos, sums, NR);
    scan_sums_k<<<1, 256, 0, stream>>>(sums, nb_ui);
    scan_final<<<nb_ui, 256, 0, stream>>>(ui_pos, sums, ui_start, ui_pos, NR);
    fill_k<<<(E_UI + 255) / 256, 256, 0, stream>>>(ui_src, ui_dst, ui_w, ui_pos, ui_e, E_UI);

    // ---- build II CSR (by dst) ----
    hipMemsetAsync(ii_pos, 0, I_N * sizeof(int), stream);
    hist_k4<<<(E_II / 4 + 255) / 256, 256, 0, stream>>>(ii_dst, ii_pos, E_II);
    scan_partial<<<nb_ii, 256, 0, stream>>>(ii_pos, sums, I_N);
    scan_sums_k<<<1, 256, 0, stream>>>(sums, nb_ii);
    scan_final<<<nb_ii, 256, 0, stream>>>(ii_pos, sums, ii_start, ii_pos, I_N);
    fill_k<<<(E_II + 255) / 256, 256, 0, stream>>>(ii_src, ii_dst, ii_w, ii_pos, ii_e, E_II);

    // ---- gis chain: gis0 = bf16(Gis); gisA = spmm(gis0); gisB = spmm(gisA) ----
    cvt_bf8<<<(int)((NI / 8 + 255) / 256), 256, 0, stream>>>(Gis, gis0, (int)(NI / 8));
    spmm_pull_bf<<<(I_N + 3) / 4, 256, 0, stream>>>(ii_start, ii_e, gis0, gisA, I_N);
    spmm_pull_f32<<<(I_N + 3) / 4, 256, 0, stream>>>(ii_start, ii_e, gisA, gisB, I_N);

    // ---- ego init: bufA(bf16) = acc(f32) = [Gu; Gi] ----
    ego_init8<<<(int)((NA / 8 + 255) / 256), 256, 0, stream>>>(Gu, Gi, bufA, acc, (int)(NA / 8));

    // ---- 3 UI layers (norm fused; last one fuses finalize) ----
    spmm_pull_norm<<<(NR + 3) / 4, 256, 0, stream>>>(ui_start, ui_e, bufA, bufB, acc, NR);
    spmm_pull_norm<<<(NR + 3) / 4, 256, 0, stream>>>(ui_start, ui_e, bufB, bufA, acc, NR);
    spmm_pull_norm_final<<<(NR + 3) / 4, 256, 0, stream>>>(ui_start, ui_e, bufA, gisB, acc, NR);
}